// Round 8
// baseline (770.355 us; speedup 1.0000x reference)
//
#include <hip/hip_runtime.h>
#include <hip/hip_bf16.h>
#include <math.h>

constexpr int BB = 2;
constexpr int NNODE = 256;   // N
constexpr int DD = 256;      // D == E
constexpr int HH = 8;
constexpr int EE = 256;
constexpr int FF = 1024;     // 4*E
constexpr int RT = 4;        // rows per block in qkv/node (weight reuse factor)

typedef __bf16 bf16x8 __attribute__((ext_vector_type(8)));
typedef float f32x4 __attribute__((ext_vector_type(4)));
typedef unsigned int uint4v __attribute__((ext_vector_type(4)));
typedef unsigned int uint2v __attribute__((ext_vector_type(2)));

// swizzle: xor low 2 bits with bits 4-5 -> spreads q-groups across bank groups
#define SWZB(x) ((x) ^ (((x) >> 4) & 3))

__device__ __forceinline__ unsigned short f2bf(float f) {
  unsigned u = __builtin_bit_cast(unsigned, f);
  unsigned r = u + 0x7FFFu + ((u >> 16) & 1u);
  return (unsigned short)(r >> 16);
}
__device__ __forceinline__ float bf2f(unsigned short us) {
  return __builtin_bit_cast(float, (unsigned)us << 16);
}
__device__ __forceinline__ bf16x8 ld_frag(const unsigned short* p) {
  uint4v u = *(const uint4v*)p;
  return __builtin_bit_cast(bf16x8, u);
}

// ---------------- merged weight-prep kernel ----------------
__device__ __forceinline__ void d_transpose(const float* __restrict__ src,
                                            float* __restrict__ dst,
                                            int rows, int cols, int idx) {
  int r = idx / cols, c = idx - r * cols;
  dst[c * rows + r] = src[idx];
}
// B-frag pack: dst[((kt*NT+nt)*64+lane)*8+j] = bf16(src[nt*16+(lane&15)][kt*32+(lane>>4)*8+j])
__device__ __forceinline__ void d_pack(const float* __restrict__ src,
                                       unsigned short* __restrict__ dst,
                                       int K, int Nn, int idx) {
  int NT = Nn >> 4;
  int lane = idx & 63, ntkt = idx >> 6;
  int nt = ntkt % NT, kt = ntkt / NT;
  int q = lane >> 4, l15 = lane & 15;
  const float* s = src + (size_t)(nt * 16 + l15) * K + kt * 32 + q * 8;
  float4 a = *(const float4*)s;
  float4 b = *(const float4*)(s + 4);
  unsigned short* d = dst + (size_t)idx * 8;
  d[0] = f2bf(a.x); d[1] = f2bf(a.y); d[2] = f2bf(a.z); d[3] = f2bf(a.w);
  d[4] = f2bf(b.x); d[5] = f2bf(b.y); d[6] = f2bf(b.z); d[7] = f2bf(b.w);
}

__global__ __launch_bounds__(256) void prep_kernel(
    const float* __restrict__ Wqkv, float* __restrict__ WqkvT,
    const float* __restrict__ Wno,  float* __restrict__ WnoT,
    const float* __restrict__ Wn1,  float* __restrict__ Wn1T,
    const float* __restrict__ Wn2,  float* __restrict__ Wn2T,
    const float* __restrict__ Weo,  unsigned short* __restrict__ Weop,
    const float* __restrict__ We1,  unsigned short* __restrict__ We1p,
    const float* __restrict__ We2,  unsigned short* __restrict__ We2p)
{
  const int blk = blockIdx.x, tid = threadIdx.x;
  if (blk < 768)        d_transpose(Wqkv, WqkvT, 768, 256, blk * 256 + tid);
  else if (blk < 1024)  d_transpose(Wno, WnoT, 256, 256, (blk - 768) * 256 + tid);
  else if (blk < 2048)  d_transpose(Wn1, Wn1T, 1024, 256, (blk - 1024) * 256 + tid);
  else if (blk < 3072)  d_transpose(Wn2, Wn2T, 256, 1024, (blk - 2048) * 256 + tid);
  else if (blk < 3104)  d_pack(Weo, Weop, 256, 256, (blk - 3072) * 256 + tid);
  else if (blk < 3232)  d_pack(We1, We1p, 256, 1024, (blk - 3104) * 256 + tid);
  else                  d_pack(We2, We2p, 1024, 256, (blk - 3232) * 256 + tid);
}

// ---------------- qkv projection, RT rows per block ----------------
// Each weight element loaded once per block, used RT times (reg accumulators).
// Grid: BB*NNODE/RT. Weight L2 traffic cut RT x vs 1-row blocks.
__global__ __launch_bounds__(256) void qkv_kernel(
    const float* __restrict__ nodes, const float* __restrict__ conds,
    const float* __restrict__ WqkvT, const float* __restrict__ bqkv,
    float* __restrict__ Q, float* __restrict__ K, float* __restrict__ V)
{
  __shared__ float sX[RT][DD];
  const int row0 = blockIdx.x * RT;
  const int b = row0 >> 8;          // RT divides 256 -> same batch for all rows
  const int tid = threadIdx.x;
  #pragma unroll
  for (int r = 0; r < RT; ++r)
    sX[r][tid] = nodes[(size_t)(row0 + r) * DD + tid] + conds[b * DD + tid];
  __syncthreads();

  float aq[RT], ak[RT], av[RT];
  #pragma unroll
  for (int r = 0; r < RT; ++r) {
    aq[r] = bqkv[tid]; ak[r] = bqkv[DD + tid]; av[r] = bqkv[2 * DD + tid];
  }
  for (int d = 0; d < DD; d += 4) {
    float4 xr[RT];
    #pragma unroll
    for (int r = 0; r < RT; ++r) xr[r] = *(const float4*)&sX[r][d];
    const float* wp = &WqkvT[d * (3 * DD)];
    const float wq0 = wp[tid],              wk0 = wp[DD + tid],              wv0 = wp[2 * DD + tid];
    const float wq1 = wp[768 + tid],        wk1 = wp[768 + DD + tid],        wv1 = wp[768 + 2 * DD + tid];
    const float wq2 = wp[1536 + tid],       wk2 = wp[1536 + DD + tid],       wv2 = wp[1536 + 2 * DD + tid];
    const float wq3 = wp[2304 + tid],       wk3 = wp[2304 + DD + tid],       wv3 = wp[2304 + 2 * DD + tid];
    #pragma unroll
    for (int r = 0; r < RT; ++r) {
      aq[r] = fmaf(xr[r].x, wq0, aq[r]); ak[r] = fmaf(xr[r].x, wk0, ak[r]); av[r] = fmaf(xr[r].x, wv0, av[r]);
      aq[r] = fmaf(xr[r].y, wq1, aq[r]); ak[r] = fmaf(xr[r].y, wk1, ak[r]); av[r] = fmaf(xr[r].y, wv1, av[r]);
      aq[r] = fmaf(xr[r].z, wq2, aq[r]); ak[r] = fmaf(xr[r].z, wk2, ak[r]); av[r] = fmaf(xr[r].z, wv2, av[r]);
      aq[r] = fmaf(xr[r].w, wq3, aq[r]); ak[r] = fmaf(xr[r].w, wk3, ak[r]); av[r] = fmaf(xr[r].w, wv3, av[r]);
    }
  }
  #pragma unroll
  for (int r = 0; r < RT; ++r) {
    Q[(size_t)(row0 + r) * DD + tid] = aq[r];
    K[(size_t)(row0 + r) * DD + tid] = ak[r];
    V[(size_t)(row0 + r) * DD + tid] = av[r];
  }
}

// ---------------- fused MFMA edge kernel (unchanged from R7: 432us best) ----------------
__global__ __launch_bounds__(512, 4) void edge_mfma_kernel(
    const float* __restrict__ Q, const float* __restrict__ K,
    const float* __restrict__ edges,
    const unsigned short* __restrict__ Weop, const float* __restrict__ beo,
    const float* __restrict__ g1e, const float* __restrict__ b1e,
    const unsigned short* __restrict__ We1p, const float* __restrict__ be1,
    const unsigned short* __restrict__ We2p, const float* __restrict__ be2,
    const float* __restrict__ g2e, const float* __restrict__ b2e,
    float* __restrict__ logits, float* __restrict__ out_edges)
{
  // pool: sAp (16384 B) + sScr (16896 B) = 33280 B; sY (32*260*4 = 33280 B) overlays both
  __shared__ __attribute__((aligned(16))) unsigned char sPool[33280];
  unsigned short* const sAp  = (unsigned short*)sPool;             // [2*8*64*8]
  unsigned short* const sScr = (unsigned short*)(sPool + 16384);   // [32*264]
  float* const sY = (float*)sPool;                                 // [32][260]
  __shared__ float sQ[256];
  __shared__ float sLog[32][8];
  __shared__ float sSum[32][8], sSsq[32][8];
  __shared__ float sMean[32], sRstd[32];

  const int tid = threadIdx.x;
  const int w = tid >> 6;            // wave 0..7
  const int lane = tid & 63;
  const int q = lane >> 4;
  const int l15 = lane & 15;
  const int lane_sw = SWZB(lane);

  const int blk = blockIdx.x;
  const int bi = blk >> 3;          // b*N + i
  const int b = bi >> 8;
  const int j0 = (blk & 7) * 32;

  // ---- phase 0: sQ ----
  if (tid < 256) sQ[tid] = Q[(size_t)bi * DD + tid] * 0.0625f;
  __syncthreads();

  // ---- phase 1 (4-wide): ne5 = q*k/16 + edges; residual bf16 -> sScr; logits partials; pack ne5 -> sAp ----
  {
    const int m = tid >> 4;          // row 0..31 (16 lanes per row)
    const int db = tid & 15;
    const size_t krow = ((size_t)(b * NNODE + j0 + m)) * DD;
    const size_t erow = ((size_t)bi * NNODE + j0 + m) * DD;
    const int mt = m >> 4;
    const int quad = (db >> 1) & 3;          // (col%32)/8
    const int half4 = (db & 1) * 4;          // j offset within frag
    const int lane2 = quad * 16 + (m & 15);
    #pragma unroll
    for (int it = 0; it < 4; ++it) {
      const int d0 = it * 64 + db * 4;       // lane covers cols d0..d0+3
      const float4 k0 = *(const float4*)&K[krow + d0];
      const float4 e0 = *(const float4*)&edges[erow + d0];
      const float4 q0 = *(const float4*)&sQ[d0];
      const float f0 = fmaf(q0.x, k0.x, e0.x);
      const float f1 = fmaf(q0.y, k0.y, e0.y);
      const float f2 = fmaf(q0.z, k0.z, e0.z);
      const float f3 = fmaf(q0.w, k0.w, e0.w);
      // edges residual, bf16, row-major stride 264 (8 B store)
      uint2v ep;
      ep.x = (unsigned)f2bf(e0.x) | ((unsigned)f2bf(e0.y) << 16);
      ep.y = (unsigned)f2bf(e0.z) | ((unsigned)f2bf(e0.w) << 16);
      *(uint2v*)&sScr[m * 264 + d0] = ep;
      // logits partial: chunk h = 2*it + (db>>3); 8-lane group covers 32 cols
      float s = f0 + f1 + f2 + f3;
      s += __shfl_xor(s, 1, 64);
      s += __shfl_xor(s, 2, 64);
      s += __shfl_xor(s, 4, 64);
      if ((db & 7) == 0) sLog[m][2 * it + (db >> 3)] = s;
      // half A-frag pack (8 B): kt = col/32, j = col%8 in {0,4}
      const int kt = 2 * it + (db >> 3);
      uint2v pk;
      pk.x = (unsigned)f2bf(f0) | ((unsigned)f2bf(f1) << 16);
      pk.y = (unsigned)f2bf(f2) | ((unsigned)f2bf(f3) << 16);
      *(uint2v*)&sAp[((mt * 8 + kt) * 64 + SWZB(lane2)) * 8 + half4] = pk;
    }
  }

  // GEMM1 B preload (issued before the barrier so loads fly during the wait)
  bf16x8 Bf[2][2];
  #pragma unroll
  for (int p = 0; p < 2; ++p)
    #pragma unroll
    for (int ntl = 0; ntl < 2; ++ntl)
      Bf[p][ntl] = ld_frag(&Weop[((size_t)((p * 16 + 2 * w + ntl) * 64 + lane)) * 8]);
  __syncthreads();

  // ---- phase 2: GEMM1  C1[32x256] = ne5 @ Weo^T, depth-2 B prefetch ----
  f32x4 acc1[2][2];
  #pragma unroll
  for (int mt = 0; mt < 2; ++mt)
    #pragma unroll
    for (int ntl = 0; ntl < 2; ++ntl)
      acc1[mt][ntl] = (f32x4){0.f, 0.f, 0.f, 0.f};
  #pragma unroll
  for (int kt = 0; kt < 8; ++kt) {
    const bf16x8 a0 = ld_frag(&sAp[((0 * 8 + kt) * 64 + lane_sw) * 8]);
    const bf16x8 a1 = ld_frag(&sAp[((1 * 8 + kt) * 64 + lane_sw) * 8]);
    const bf16x8 b0 = Bf[kt & 1][0], b1 = Bf[kt & 1][1];
    if (kt < 6) {
      #pragma unroll
      for (int ntl = 0; ntl < 2; ++ntl)
        Bf[kt & 1][ntl] = ld_frag(&Weop[((size_t)(((kt + 2) * 16 + 2 * w + ntl) * 64 + lane)) * 8]);
    }
    __builtin_amdgcn_s_setprio(1);
    acc1[0][0] = __builtin_amdgcn_mfma_f32_16x16x32_bf16(a0, b0, acc1[0][0], 0, 0, 0);
    acc1[1][0] = __builtin_amdgcn_mfma_f32_16x16x32_bf16(a1, b0, acc1[1][0], 0, 0, 0);
    acc1[0][1] = __builtin_amdgcn_mfma_f32_16x16x32_bf16(a0, b1, acc1[0][1], 0, 0, 0);
    acc1[1][1] = __builtin_amdgcn_mfma_f32_16x16x32_bf16(a1, b1, acc1[1][1], 0, 0, 0);
    __builtin_amdgcn_s_setprio(0);
  }

  // logits out (off the critical path; sLog ordered by the phase-1 barrier)
  if (tid < 256) {
    const int h = tid >> 5, mm = tid & 31;
    logits[((size_t)bi * HH + h) * NNODE + j0 + mm] = sLog[mm][h];
  }

  // ---- phase 3: acc1 := tpre = relu(C1+beo) + edges; LN1; t -> sAp ----
  #pragma unroll
  for (int ntl = 0; ntl < 2; ++ntl) {
    const int col = w * 32 + ntl * 16 + l15;
    const float beoc = beo[col];
    #pragma unroll
    for (int mt = 0; mt < 2; ++mt) {
      #pragma unroll
      for (int r = 0; r < 4; ++r) {
        const int m_ = mt * 16 + q * 4 + r;
        const float ed = bf2f(sScr[m_ * 264 + col]);
        acc1[mt][ntl][r] = fmaxf(acc1[mt][ntl][r] + beoc, 0.f) + ed;
      }
    }
  }
  #pragma unroll
  for (int mt = 0; mt < 2; ++mt) {
    #pragma unroll
    for (int r = 0; r < 4; ++r) {
      float s = acc1[mt][0][r] + acc1[mt][1][r];
      float ss = acc1[mt][0][r] * acc1[mt][0][r] + acc1[mt][1][r] * acc1[mt][1][r];
      #pragma unroll
      for (int off = 1; off < 16; off <<= 1) {
        s += __shfl_xor(s, off, 64);
        ss += __shfl_xor(ss, off, 64);
      }
      if (l15 == 0) {
        const int m_ = mt * 16 + q * 4 + r;
        sSum[m_][w] = s; sSsq[m_][w] = ss;
      }
    }
  }
  __syncthreads();
  if (tid < 32) {
    float S = 0.f, SS = 0.f;
    #pragma unroll
    for (int i = 0; i < 8; ++i) { S += sSum[tid][i]; SS += sSsq[tid][i]; }
    const float mn = S * (1.f / 256.f);
    sMean[tid] = mn;
    sRstd[tid] = rsqrtf(SS * (1.f / 256.f) - mn * mn + 1e-5f);
  }
  __syncthreads();
  #pragma unroll
  for (int ntl = 0; ntl < 2; ++ntl) {
    const int col = w * 32 + ntl * 16 + l15;     // col>>5 == w
    const float g1 = g1e[col], b1 = b1e[col];
    const int quad2 = (col >> 3) & 3;
    const int jj = col & 7;
    #pragma unroll
    for (int mt = 0; mt < 2; ++mt) {
      #pragma unroll
      for (int r = 0; r < 4; ++r) {
        const int m_ = mt * 16 + q * 4 + r;
        const float tn = (acc1[mt][ntl][r] - sMean[m_]) * sRstd[m_] * g1 + b1;
        const int lane2 = quad2 * 16 + q * 4 + r;
        sAp[((mt * 8 + w) * 64 + SWZB(lane2)) * 8 + jj] = f2bf(tn);
      }
    }
  }
  // GEMM2 c=0 B preload before the barrier
  #pragma unroll
  for (int p = 0; p < 2; ++p)
    #pragma unroll
    for (int ntl = 0; ntl < 2; ++ntl)
      Bf[p][ntl] = ld_frag(&We1p[((size_t)((p * 64 + 0 * 16 + 2 * w + ntl) * 64 + lane)) * 8]);
  __syncthreads();

  // ---- phase 4: chunked MLP: acc3 = relu(t@We1)@We2 ----
  f32x4 acc3[2][2];
  #pragma unroll
  for (int mt = 0; mt < 2; ++mt)
    #pragma unroll
    for (int ntl = 0; ntl < 2; ++ntl)
      acc3[mt][ntl] = (f32x4){0.f, 0.f, 0.f, 0.f};

  #pragma unroll 1
  for (int c = 0; c < 4; ++c) {
    // GEMM2: h1chunk[32x256] = t @ We1^T[:, 256c:256c+256], depth-2 prefetch
    f32x4 acc2[2][2];
    #pragma unroll
    for (int mt = 0; mt < 2; ++mt)
      #pragma unroll
      for (int ntl = 0; ntl < 2; ++ntl)
        acc2[mt][ntl] = (f32x4){0.f, 0.f, 0.f, 0.f};
    #pragma unroll
    for (int kt = 0; kt < 8; ++kt) {
      const bf16x8 a0 = ld_frag(&sAp[((0 * 8 + kt) * 64 + lane_sw) * 8]);
      const bf16x8 a1 = ld_frag(&sAp[((1 * 8 + kt) * 64 + lane_sw) * 8]);
      const bf16x8 b0 = Bf[kt & 1][0], b1 = Bf[kt & 1][1];
      if (kt < 6) {
        #pragma unroll
        for (int ntl = 0; ntl < 2; ++ntl)
          Bf[kt & 1][ntl] = ld_frag(&We1p[((size_t)(((kt + 2) * 64 + c * 16 + 2 * w + ntl) * 64 + lane)) * 8]);
      }
      __builtin_amdgcn_s_setprio(1);
      acc2[0][0] = __builtin_amdgcn_mfma_f32_16x16x32_bf16(a0, b0, acc2[0][0], 0, 0, 0);
      acc2[1][0] = __builtin_amdgcn_mfma_f32_16x16x32_bf16(a1, b0, acc2[1][0], 0, 0, 0);
      acc2[0][1] = __builtin_amdgcn_mfma_f32_16x16x32_bf16(a0, b1, acc2[0][1], 0, 0, 0);
      acc2[1][1] = __builtin_amdgcn_mfma_f32_16x16x32_bf16(a1, b1, acc2[1][1], 0, 0, 0);
      __builtin_amdgcn_s_setprio(0);
    }
    // GEMM3 B preload (independent of sScr; flies across the barrier + pack)
    #pragma unroll
    for (int p = 0; p < 2; ++p)
      #pragma unroll
      for (int ntl = 0; ntl < 2; ++ntl)
        Bf[p][ntl] = ld_frag(&We2p[((size_t)(((c * 8 + p) * 16 + 2 * w + ntl) * 64 + lane)) * 8]);
    __syncthreads();   // prior GEMM3 (or phase-3 residual) reads of sScr complete
    // h1 = relu(acc2 + be1) -> bf16 -> sScr (swizzled A-frag layout); wave w writes kt=w slice
    #pragma unroll
    for (int ntl = 0; ntl < 2; ++ntl) {
      const int flocal = w * 32 + ntl * 16 + l15;
      const float bias = be1[c * 256 + flocal];
      const int quad2 = (ntl * 2 + (l15 >> 3)) & 3;
      const int jj = l15 & 7;
      #pragma unroll
      for (int mt = 0; mt < 2; ++mt) {
        #pragma unroll
        for (int r = 0; r < 4; ++r) {
          const int lane2 = quad2 * 16 + q * 4 + r;
          const float h = fmaxf(acc2[mt][ntl][r] + bias, 0.f);
          sScr[((mt * 8 + w) * 64 + SWZB(lane2)) * 8 + jj] = f2bf(h);
        }
      }
    }
    __syncthreads();
    // GEMM3 accumulate: out += h1chunk @ We2^T[f-chunk], depth-2 prefetch
    #pragma unroll
    for (int kt2 = 0; kt2 < 8; ++kt2) {
      const bf16x8 a0 = ld_frag(&sScr[((0 * 8 + kt2) * 64 + lane_sw) * 8]);
      const bf16x8 a1 = ld_frag(&sScr[((1 * 8 + kt2) * 64 + lane_sw) * 8]);
      const bf16x8 b0 = Bf[kt2 & 1][0], b1 = Bf[kt2 & 1][1];
      if (kt2 < 6) {
        #pragma unroll
        for (int ntl = 0; ntl < 2; ++ntl)
          Bf[kt2 & 1][ntl] = ld_frag(&We2p[((size_t)(((c * 8 + kt2 + 2) * 16 + 2 * w + ntl) * 64 + lane)) * 8]);
      } else if (c < 3) {
        // GEMM2 preload for next c
        #pragma unroll
        for (int ntl = 0; ntl < 2; ++ntl)
          Bf[kt2 & 1][ntl] = ld_frag(&We1p[((size_t)(((kt2 - 6) * 64 + (c + 1) * 16 + 2 * w + ntl) * 64 + lane)) * 8]);
      }
      __builtin_amdgcn_s_setprio(1);
      acc3[0][0] = __builtin_amdgcn_mfma_f32_16x16x32_bf16(a0, b0, acc3[0][0], 0, 0, 0);
      acc3[1][0] = __builtin_amdgcn_mfma_f32_16x16x32_bf16(a1, b0, acc3[1][0], 0, 0, 0);
      acc3[0][1] = __builtin_amdgcn_mfma_f32_16x16x32_bf16(a0, b1, acc3[0][1], 0, 0, 0);
      acc3[1][1] = __builtin_amdgcn_mfma_f32_16x16x32_bf16(a1, b1, acc3[1][1], 0, 0, 0);
      __builtin_amdgcn_s_setprio(0);
    }
  }

  // ---- phase 5: acc3 += be2 + t (ypre in place); LN2; staged store ----
  #pragma unroll
  for (int ntl = 0; ntl < 2; ++ntl) {
    const int col = w * 32 + ntl * 16 + l15;     // col>>5 == w
    const float be2c = be2[col];
    const int quad2 = (col >> 3) & 3;
    const int jj = col & 7;
    #pragma unroll
    for (int mt = 0; mt < 2; ++mt) {
      #pragma unroll
      for (int r = 0; r < 4; ++r) {
        const int lane2 = quad2 * 16 + q * 4 + r;
        const float tres = bf2f(sAp[((mt * 8 + w) * 64 + SWZB(lane2)) * 8 + jj]);
        acc3[mt][ntl][r] += be2c + tres;
      }
    }
  }
  #pragma unroll
  for (int mt = 0; mt < 2; ++mt) {
    #pragma unroll
    for (int r = 0; r < 4; ++r) {
      float s = acc3[mt][0][r] + acc3[mt][1][r];
      float ss = acc3[mt][0][r] * acc3[mt][0][r] + acc3[mt][1][r] * acc3[mt][1][r];
      #pragma unroll
      for (int off = 1; off < 16; off <<= 1) {
        s += __shfl_xor(s, off, 64);
        ss += __shfl_xor(ss, off, 64);
      }
      if (l15 == 0) {
        const int m_ = mt * 16 + q * 4 + r;
        sSum[m_][w] = s; sSsq[m_][w] = ss;
      }
    }
  }
  __syncthreads();       // also: all sAp (tres) reads complete -> sY may overlay
  if (tid < 32) {
    float S = 0.f, SS = 0.f;
    #pragma unroll
    for (int i = 0; i < 8; ++i) { S += sSum[tid][i]; SS += sSsq[tid][i]; }
    const float mn = S * (1.f / 256.f);
    sMean[tid] = mn;
    sRstd[tid] = rsqrtf(SS * (1.f / 256.f) - mn * mn + 1e-5f);
  }
  __syncthreads();
  // normalized y -> sY [32][260] (2-way banks = free)
  #pragma unroll
  for (int ntl = 0; ntl < 2; ++ntl) {
    const int col = w * 32 + ntl * 16 + l15;
    const float g2 = g2e[col], b2v = b2e[col];
    #pragma unroll
    for (int mt = 0; mt < 2; ++mt) {
      #pragma unroll
      for (int r = 0; r < 4; ++r) {
        const int m_ = mt * 16 + q * 4 + r;
        sY[m_ * 260 + col] = (acc3[mt][ntl][r] - sMean[m_]) * sRstd[m_] * g2 + b2v;
      }
    }
  }
  __syncthreads();
  // coalesced float4 stores: 64 lanes x 16B = full 1KB rows (full 128B lines)
  {
    const int c4 = (tid & 63) * 4;
    #pragma unroll
    for (int p = 0; p < 4; ++p) {
      const int row = p * 8 + w;
      const float4 v = *(const float4*)&sY[row * 260 + c4];
      *(float4*)&out_edges[((size_t)bi * NNODE + j0 + row) * EE + c4] = v;
    }
  }
}

// ---------------- softmax ----------------
__global__ __launch_bounds__(64) void softmax_kernel(float* __restrict__ logits) {
  const int row = blockIdx.x;
  const int l = threadIdx.x;
  float* p = logits + (size_t)row * NNODE;
  float v0 = p[l], v1 = p[l + 64], v2 = p[l + 128], v3 = p[l + 192];
  float m = fmaxf(fmaxf(v0, v1), fmaxf(v2, v3));
  #pragma unroll
  for (int off = 32; off > 0; off >>= 1) m = fmaxf(m, __shfl_xor(m, off, 64));
  const float e0 = __expf(v0 - m), e1 = __expf(v1 - m), e2 = __expf(v2 - m), e3 = __expf(v3 - m);
  float s = e0 + e1 + e2 + e3;
  #pragma unroll
  for (int off = 32; off > 0; off >>= 1) s += __shfl_xor(s, off, 64);
  const float inv = 1.f / s;
  p[l] = e0 * inv; p[l + 64] = e1 * inv; p[l + 128] = e2 * inv; p[l + 192] = e3 * inv;
}

// ---------------- fused node path, RT rows per block ----------------
// Each weight element (WnoT/Wn1T/Wn2T) and V element loaded once per block,
// reused RT x in registers. Grid: BB*NNODE/RT = 128 blocks. Cuts node-path
// weight L2 streaming from 1.28 GB to 320 MB and gives 4-chain ILP.
__global__ __launch_bounds__(256) void node_kernel(
    const float* __restrict__ attn, const float* __restrict__ V,
    const float* __restrict__ nodes,
    const float* __restrict__ WnoT, const float* __restrict__ bno,
    const float* __restrict__ g1n, const float* __restrict__ b1n,
    const float* __restrict__ Wn1T, const float* __restrict__ bn1,
    const float* __restrict__ Wn2T, const float* __restrict__ bn2,
    const float* __restrict__ g2n, const float* __restrict__ b2n,
    float* __restrict__ out_nodes)
{
  __shared__ float sA[RT][HH][NNODE];   // 32 KB
  __shared__ float sX[RT][DD];          // 4 KB
  __shared__ float sH[RT][FF];          // 16 KB
  __shared__ float red[RT][8];
  __shared__ float mv2[RT][2];

  const int row0 = blockIdx.x * RT;
  const int b = row0 >> 8;              // RT divides 256 -> same batch
  const int tid = threadIdx.x;

  for (int t = tid; t < RT * HH * NNODE; t += 256) {
    const int r = t >> 11;              // 2048 = HH*NNODE per row
    const int rem = t & 2047;
    sA[r][rem >> 8][rem & 255] = attn[(size_t)(row0 + r) * (HH * NNODE) + rem];
  }
  __syncthreads();

  const int h = tid >> 5;
  float wv[RT];
  #pragma unroll
  for (int r = 0; r < RT; ++r) wv[r] = 0.f;
  #pragma unroll 4
  for (int j = 0; j < NNODE; ++j) {
    const float v = V[(size_t)(b * NNODE + j) * DD + tid];
    #pragma unroll
    for (int r = 0; r < RT; ++r) wv[r] = fmaf(sA[r][h][j], v, wv[r]);
  }
  __syncthreads();   // sA dead after this point is NOT true (reads above done per-thread) — barrier orders sX writes below anyway
  #pragma unroll
  for (int r = 0; r < RT; ++r) sX[r][tid] = wv[r];
  __syncthreads();

  // a1[r][tid] = bno[tid] + sum_d sX[r][d]*WnoT[d][tid]  (+ nodes residual)
  float a1[RT];
  #pragma unroll
  for (int r = 0; r < RT; ++r) a1[r] = bno[tid];
  for (int d = 0; d < DD; d += 4) {
    float4 xr[RT];
    #pragma unroll
    for (int r = 0; r < RT; ++r) xr[r] = *(const float4*)&sX[r][d];
    const float* wp = &WnoT[d * DD + tid];
    const float w0 = wp[0], w1 = wp[DD], w2 = wp[2 * DD], w3 = wp[3 * DD];
    #pragma unroll
    for (int r = 0; r < RT; ++r) {
      a1[r] = fmaf(xr[r].x, w0, a1[r]);
      a1[r] = fmaf(xr[r].y, w1, a1[r]);
      a1[r] = fmaf(xr[r].z, w2, a1[r]);
      a1[r] = fmaf(xr[r].w, w3, a1[r]);
    }
  }
  #pragma unroll
  for (int r = 0; r < RT; ++r) a1[r] += nodes[(size_t)(row0 + r) * DD + tid];

  // LN1 (per row)
  #pragma unroll
  for (int r = 0; r < RT; ++r) {
    float s = a1[r], ss = a1[r] * a1[r];
    #pragma unroll
    for (int off = 32; off > 0; off >>= 1) { s += __shfl_xor(s, off, 64); ss += __shfl_xor(ss, off, 64); }
    if ((tid & 63) == 0) { red[r][tid >> 6] = s; red[r][4 + (tid >> 6)] = ss; }
  }
  __syncthreads();
  if (tid < RT) {
    const float S = red[tid][0] + red[tid][1] + red[tid][2] + red[tid][3];
    const float SS = red[tid][4] + red[tid][5] + red[tid][6] + red[tid][7];
    const float m = S * (1.f / 256.f);
    mv2[tid][0] = m; mv2[tid][1] = rsqrtf(SS * (1.f / 256.f) - m * m + 1e-5f);
  }
  __syncthreads();
  float x1[RT];
  #pragma unroll
  for (int r = 0; r < RT; ++r) {
    x1[r] = (a1[r] - mv2[r][0]) * mv2[r][1] * g1n[tid] + b1n[tid];
    sX[r][tid] = x1[r];
  }
  __syncthreads();

  // h1[p][r] over 4 col-chunks of FF
  float h1[4][RT];
  #pragma unroll
  for (int p = 0; p < 4; ++p)
    #pragma unroll
    for (int r = 0; r < RT; ++r) h1[p][r] = bn1[p * 256 + tid];
  for (int d = 0; d < DD; d += 4) {
    float4 xr[RT];
    #pragma unroll
    for (int r = 0; r < RT; ++r) xr[r] = *(const float4*)&sX[r][d];
    #pragma unroll
    for (int p = 0; p < 4; ++p) {
      const float* wp = &Wn1T[d * FF + p * 256 + tid];
      const float w0 = wp[0], w1 = wp[FF], w2 = wp[2 * FF], w3 = wp[3 * FF];
      #pragma unroll
      for (int r = 0; r < RT; ++r) {
        h1[p][r] = fmaf(xr[r].x, w0, h1[p][r]);
        h1[p][r] = fmaf(xr[r].y, w1, h1[p][r]);
        h1[p][r] = fmaf(xr[r].z, w2, h1[p][r]);
        h1[p][r] = fmaf(xr[r].w, w3, h1[p][r]);
      }
    }
  }
  #pragma unroll
  for (int p = 0; p < 4; ++p)
    #pragma unroll
    for (int r = 0; r < RT; ++r) sH[r][p * 256 + tid] = fmaxf(h1[p][r], 0.f);
  __syncthreads();

  float a2[RT];
  #pragma unroll
  for (int r = 0; r < RT; ++r) a2[r] = bn2[tid];
  for (int f = 0; f < FF; f += 4) {
    float4 xr[RT];
    #pragma unroll
    for (int r = 0; r < RT; ++r) xr[r] = *(const float4*)&sH[r][f];
    const float* wp = &Wn2T[f * DD + tid];
    const float w0 = wp[0], w1 = wp[DD], w2 = wp[2 * DD], w3 = wp[3 * DD];
    #pragma unroll
    for (int r = 0; r < RT; ++r) {
      a2[r] = fmaf(xr[r].x, w0, a2[r]);
      a2[r] = fmaf(xr[r].y, w1, a2[r]);
      a2[r] = fmaf(xr[r].z, w2, a2[r]);
      a2[r] = fmaf(xr[r].w, w3, a2[r]);
    }
  }
  #pragma unroll
  for (int r = 0; r < RT; ++r) a2[r] += x1[r];

  // LN2 (per row) + store
  #pragma unroll
  for (int r = 0; r < RT; ++r) {
    float s = a2[r], ss = a2[r] * a2[r];
    #pragma unroll
    for (int off = 32; off > 0; off >>= 1) { s += __shfl_xor(s, off, 64); ss += __shfl_xor(ss, off, 64); }
    if ((tid & 63) == 0) { red[r][tid >> 6] = s; red[r][4 + (tid >> 6)] = ss; }
  }
  __syncthreads();
  if (tid < RT) {
    const float S = red[tid][0] + red[tid][1] + red[tid][2] + red[tid][3];
    const float SS = red[tid][4] + red[tid][5] + red[tid][6] + red[tid][7];
    const float m = S * (1.f / 256.f);
    mv2[tid][0] = m; mv2[tid][1] = rsqrtf(SS * (1.f / 256.f) - m * m + 1e-5f);
  }
  __syncthreads();
  #pragma unroll
  for (int r = 0; r < RT; ++r)
    out_nodes[(size_t)(row0 + r) * DD + tid] =
        (a2[r] - mv2[r][0]) * mv2[r][1] * g2n[tid] + b2n[tid];
}

extern "C" void kernel_launch(void* const* d_in, const int* in_sizes, int n_in,
                              void* d_out, int out_size, void* d_ws, size_t ws_size,
                              hipStream_t stream) {
  const float* nodes = (const float*)d_in[0];
  const float* edges = (const float*)d_in[1];
  const float* conds = (const float*)d_in[2];
  const float* Wqkv = (const float*)d_in[3];
  const float* bqkv = (const float*)d_in[4];
  const float* Wno  = (const float*)d_in[5];
  const float* bno  = (const float*)d_in[6];
  const float* Weo  = (const float*)d_in[7];
  const float* beo  = (const float*)d_in[8];
  const float* g1n  = (const float*)d_in[9];
  const float* b1n  = (const float*)d_in[10];
  const float* g1e  = (const float*)d_in[11];
  const float* b1e  = (const float*)d_in[12];
  const float* Wn1  = (const float*)d_in[13];
  const float* bn1  = (const float*)d_in[14];
  const float* Wn2  = (const float*)d_in[15];
  const float* bn2  = (const float*)d_in[16];
  const float* We1  = (const float*)d_in[17];
  const float* be1  = (const float*)d_in[18];
  const float* We2  = (const float*)d_in[19];
  const float* be2  = (const float*)d_in[20];
  const float* g2n  = (const float*)d_in[21];
  const float* b2n  = (const float*)d_in[22];
  const float* g2e  = (const float*)d_in[23];
  const float* b2e  = (const float*)d_in[24];

  float* ws = (float*)d_ws;
  float* Q = ws;
  float* K = Q + BB * NNODE * DD;
  float* V = K + BB * NNODE * DD;
  float* logits = V + BB * NNODE * DD;                 // B*N*H*N
  float* WqkvT = logits + BB * NNODE * HH * NNODE;
  float* WnoT = WqkvT + 3 * DD * DD;
  float* Wn1T = WnoT + DD * DD;
  float* Wn2T = Wn1T + DD * FF;
  unsigned short* Weop = (unsigned short*)(Wn2T + FF * DD);
  unsigned short* We1p = Weop + EE * DD;
  unsigned short* We2p = We1p + FF * DD;

  float* out_nodes = (float*)d_out;
  float* out_edges = out_nodes + BB * NNODE * DD;
  float* out_conds = out_edges + (size_t)BB * NNODE * NNODE * EE;

  prep_kernel<<<3360, 256, 0, stream>>>(
      Wqkv, WqkvT, Wno, WnoT, Wn1, Wn1T, Wn2, Wn2T,
      Weo, Weop, We1, We1p, We2, We2p);

  qkv_kernel<<<BB * NNODE / RT, 256, 0, stream>>>(nodes, conds, WqkvT, bqkv, Q, K, V);
  edge_mfma_kernel<<<BB * NNODE * (NNODE / 32), 512, 0, stream>>>(
      Q, K, edges, Weop, beo, g1e, b1e, We1p, be1, We2p, be2, g2e, b2e,
      logits, out_edges);
  softmax_kernel<<<BB * NNODE * HH, 64, 0, stream>>>(logits);
  node_kernel<<<BB * NNODE / RT, 256, 0, stream>>>(
      logits, V, nodes, WnoT, bno, g1n, b1n, Wn1T, bn1, Wn2T, bn2, g2n, b2n,
      out_nodes);

  hipMemcpyAsync(out_conds, conds, BB * DD * sizeof(float),
                 hipMemcpyDeviceToDevice, stream);
}